// Round 9
// baseline (535.859 us; speedup 1.0000x reference)
//
#include <hip/hip_runtime.h>
#include <hip/hip_bf16.h>
#include <cstdint>
#include <cstddef>

typedef unsigned short u16;
typedef unsigned int u32;
typedef short short8 __attribute__((ext_vector_type(8)));
typedef short short4v __attribute__((ext_vector_type(4)));
typedef __bf16 bf16x8 __attribute__((ext_vector_type(8)));
typedef float v4f __attribute__((ext_vector_type(4)));
typedef float v16f __attribute__((ext_vector_type(16)));

#define NSAMP 65536
#define FEAT_PAD 1824   // 228 groups of 8

// ---- Layouts ----
// feats_t [rt=s>>4][g=kp>>3][r=s&15][e=kp&7]: elem addr = rt*29184 + g*128 + r*8 + e
// w1t_t   [ct=n>>4][g][c][e]:                 addr = ct*29184 + g*128 + c*8 + e
// h1      ROW-MAJOR [s][n] (65536 x 256)
// w2t_t   [ct][g][c][e] (128 cols, K=256):    addr = ct*4096  + g*128 + c*8 + e
// w3t_t   [ct][g][c][e] (64 cols, K=128):     addr = ct*2048  + g*128 + c*8 + e
// Intra-gram kp permutation (validated R3-R8):
//   kp in [512,1536): kp = 512 + lane*16 + rr  <-> orig 512 + i*32 + j,
//        j=lane&31, i=(rr&3)+8*(rr>>2)+4*(lane>>5)
//   kp in [1536,1792): kp = 1536 + lane*4 + rr <-> orig 1536 + i*16 + j,
//        j=lane&15, i=(lane>>4)*4+rr
//   sv at kp [1792,1808) natural, zeros [1808,1824)

__device__ __forceinline__ u16 f2bf(float f) {
  union { float f; u32 u; } v; v.f = f;
  u32 r = (v.u + 0x7FFFu + ((v.u >> 16) & 1u)) >> 16;  // RTNE
  return (u16)r;
}
__device__ __forceinline__ float bf2f(u16 h) {
  union { u32 u; float f; } v; v.u = ((u32)h) << 16;
  return v.f;
}

__device__ __forceinline__ v4f mfma16(short8 a, short8 b, v4f c) {
  return __builtin_amdgcn_mfma_f32_16x16x32_bf16(
      __builtin_bit_cast(bf16x8, a), __builtin_bit_cast(bf16x8, b), c, 0, 0, 0);
}
__device__ __forceinline__ v16f mfma32(short8 a, short8 b, v16f c) {
  return __builtin_amdgcn_mfma_f32_32x32x16_bf16(
      __builtin_bit_cast(bf16x8, a), __builtin_bit_cast(bf16x8, b), c, 0, 0, 0);
}

// async global->LDS, 16 B/lane; per-lane global addr, wave-uniform LDS base
typedef __attribute__((address_space(1))) const void* gas_ptr;
typedef __attribute__((address_space(3))) void* las_ptr;
__device__ __forceinline__ void gl_lds16(const void* g, void* l) {
  __builtin_amdgcn_global_load_lds((gas_ptr)g, (las_ptr)l, 16, 0, 0);
}

// ---------------------------------------------------------------------------
// Weight prep -> fragment-tiled W1t/W2t/W3t. (unchanged)
// ---------------------------------------------------------------------------
__global__ void prep_kernel(const float* __restrict__ W1, const float* __restrict__ W2,
                            const float* __restrict__ W3,
                            u16* __restrict__ w1t, u16* __restrict__ w2t, u16* __restrict__ w3t) {
  int idx = blockIdx.x * 256 + threadIdx.x;
  if (idx < 256 * FEAT_PAD) {
    int n = idx / FEAT_PAD, kp = idx % FEAT_PAD;
    int k;
    if (kp < 512) {
      k = kp;
    } else if (kp < 1536) {
      int t = kp - 512, ln = t >> 4, rr = t & 15;
      int jj = ln & 31, q2 = ln >> 5;
      int i = (rr & 3) + 8 * (rr >> 2) + 4 * q2;
      k = 512 + i * 32 + jj;
    } else if (kp < 1792) {
      int t = kp - 1536, ln = t >> 2, rr = t & 3;
      int jj = ln & 15;
      int i = (ln >> 4) * 4 + rr;
      k = 1536 + i * 16 + jj;
    } else {
      k = kp;
    }
    size_t addr = (size_t)(n >> 4) * 29184 + (kp >> 3) * 128 + (n & 15) * 8 + (kp & 7);
    w1t[addr] = (kp < 1808) ? f2bf(W1[(size_t)k * 256 + n]) : (u16)0;
  }
  if (idx < 128 * 256) {
    int n = idx / 256, k = idx % 256;
    size_t addr = (size_t)(n >> 4) * 4096 + (k >> 3) * 128 + (n & 15) * 8 + (k & 7);
    w2t[addr] = f2bf(W2[k * 128 + n]);
  }
  if (idx < 64 * 128) {
    int n = idx / 128, k = idx % 128;
    size_t addr = (size_t)(n >> 4) * 2048 + (k >> 3) * 128 + (n & 15) * 8 + (k & 7);
    w3t[addr] = f2bf(W3[k * 64 + n]);
  }
}

// ---------------------------------------------------------------------------
// Feature kernel: ONE 4-sample qtr per wave. (unchanged R8)
// ---------------------------------------------------------------------------
__global__ __launch_bounds__(256) void feat_kernel(const float* __restrict__ x,
                                                   u16* __restrict__ feats) {
  const int lane = threadIdx.x & 63;
  const int wv = threadIdx.x >> 6;      // qtr index 0..3
  const int wid = blockIdx.x;           // tile 0..4095
  const int l15 = lane & 15, l31 = lane & 31, q4 = lane >> 4, q2 = lane >> 5;
  const int pbase = l15 * 32 + q4 * 8;
  u16* tb = feats + (size_t)wid * 29184;

  short8 sx[4], sc0[4], sc1[4];
  short4v sr4[4];
#pragma unroll
  for (int r8 = 0; r8 < 4; ++r8) {
    const int s = wid * 16 + wv * 4 + r8;
    const float* xs = x + (size_t)s * 512;
    float4 p0 = *(const float4*)(xs + pbase);
    float4 p1 = *(const float4*)(xs + pbase + 4);
    float t[8];
#pragma unroll
    for (int j = 0; j < 8; ++j) t[j] = xs[(q2 * 8 + j) * 32 + l31];

    short8 fp, ft;
    fp[0] = (short)f2bf(p0.x); fp[1] = (short)f2bf(p0.y);
    fp[2] = (short)f2bf(p0.z); fp[3] = (short)f2bf(p0.w);
    fp[4] = (short)f2bf(p1.x); fp[5] = (short)f2bf(p1.y);
    fp[6] = (short)f2bf(p1.z); fp[7] = (short)f2bf(p1.w);
#pragma unroll
    for (int j = 0; j < 8; ++j) ft[j] = (short)f2bf(t[j]);

    v4f accR; v16f accC;
#pragma unroll
    for (int r = 0; r < 4; ++r) accR[r] = 0.f;
#pragma unroll
    for (int r = 0; r < 16; ++r) accC[r] = 0.f;
    accR = mfma16(fp, fp, accR);   // Gr = P P^T
    accC = mfma32(ft, ft, accC);   // Gc = P^T P

    sx[r8] = fp;
#pragma unroll
    for (int r = 0; r < 8; ++r) { sc0[r8][r] = (short)f2bf(accC[r]); sc1[r8][r] = (short)f2bf(accC[r + 8]); }
#pragma unroll
    for (int r = 0; r < 4; ++r) sr4[r8][r] = (short)f2bf(accR[r]);
  }

  const int ho = wv * 4;
#pragma unroll
  for (int r8 = 0; r8 < 4; ++r8)
    *(short8*)(tb + (l15 * 4 + q4) * 128 + (ho + r8) * 8) = sx[r8];
#pragma unroll
  for (int r8 = 0; r8 < 4; ++r8)
    *(short8*)(tb + (64 + lane * 2) * 128 + (ho + r8) * 8) = sc0[r8];
#pragma unroll
  for (int r8 = 0; r8 < 4; ++r8)
    *(short8*)(tb + (65 + lane * 2) * 128 + (ho + r8) * 8) = sc1[r8];
#pragma unroll
  for (int r8 = 0; r8 < 4; ++r8)
    *(short4v*)(tb + (192 + (lane >> 1)) * 128 + (lane & 1) * 4 + (ho + r8) * 8) = sr4[r8];

  if (wv == 3 && lane < 32) {  // zero pad groups 226,227
    short8 z;
#pragma unroll
    for (int j = 0; j < 8; ++j) z[j] = 0;
    *(short8*)(tb + 226 * 128 + lane * 8) = z;
  }
}

// ---------------------------------------------------------------------------
// SVD kernel, lane-parallel, standalone. (unchanged)
// ---------------------------------------------------------------------------
__global__ __launch_bounds__(256) void svd_kernel(u16* __restrict__ feats) {
  const int tid = threadIdx.x;
  const int lane = tid & 63;
  const int j = lane & 15;
  const int bse = lane & 48;
  const int w = (blockIdx.x * 256 + tid) >> 6;
  const int s = w * 4 + ((lane >> 4) & 3);
  u16* fb = feats + (size_t)(s >> 4) * 29184 + (s & 15) * 8;

  float a[16];
#pragma unroll
  for (int gi = 0; gi < 4; ++gi) {
    ushort4 v = *(const ushort4*)(fb + (192 + gi * 8 + (j >> 1)) * 128 + (j & 1) * 4);
    a[gi * 4 + 0] = bf2f(v.x); a[gi * 4 + 1] = bf2f(v.y);
    a[gi * 4 + 2] = bf2f(v.z); a[gi * 4 + 3] = bf2f(v.w);
  }

  float es[16];
#pragma unroll
  for (int i = 0; i < 16; ++i) es[i] = 0.f;

#pragma unroll
  for (int step = 0; step < 14; ++step) {
    const int i = 15 - step, l = i - 1;
    float xv = a[i];
    float xm = (j <= l) ? xv : 0.f;
    float h = xm * xm;
    h += __shfl_xor(h, 1); h += __shfl_xor(h, 2);
    h += __shfl_xor(h, 4); h += __shfl_xor(h, 8);
    float ul = __shfl(xm, bse + l);
    float sq = sqrtf(h);
    float alpha = (ul >= 0.f) ? -sq : sq;
    float denom = h - ul * alpha;
    float beta = (h > 1e-30f) ? (1.0f / denom) : 0.f;
    float v = (j < l) ? xm : ((j == l) ? (xm - alpha) : 0.f);
    float vv[16], pp[16];
#pragma unroll
    for (int m = 0; m < 16; ++m) vv[m] = (m < i) ? __shfl(v, bse + m) : 0.f;
    float p = 0.f;
#pragma unroll
    for (int m = 0; m < 16; ++m) if (m < i) p = fmaf(a[m], vv[m], p);
    p *= beta;
#pragma unroll
    for (int m = 0; m < 16; ++m) pp[m] = (m <= i) ? __shfl(p, bse + m) : 0.f;
    float Ks = 0.f;
#pragma unroll
    for (int m = 0; m < 16; ++m) if (m < i) Ks = fmaf(pp[m], vv[m], Ks);
    Ks *= 0.5f * beta;
    float wsc = p - Ks * v;
#pragma unroll
    for (int m = 0; m <= 15; ++m) {
      if (m <= i) {
        float wm = pp[m] - Ks * vv[m];
        a[m] -= vv[m] * wsc + wm * v;
      }
    }
    es[i] = alpha;
  }
  es[1] = __shfl(a[1], bse + 0);

  float dsel = a[0];
#pragma unroll
  for (int m = 1; m < 16; ++m) dsel = (j == m) ? a[m] : dsel;
  float dd[16];
#pragma unroll
  for (int m = 0; m < 16; ++m) dd[m] = __shfl(dsel, bse + m);
  float e2a[16];
  e2a[0] = 0.f;
#pragma unroll
  for (int k = 1; k < 16; ++k) e2a[k] = es[k] * es[k] + 1e-30f;
  float dmax = dd[0], emax = 0.f;
#pragma unroll
  for (int m = 1; m < 16; ++m) dmax = fmaxf(dmax, dd[m]);
#pragma unroll
  for (int k = 1; k < 16; ++k) emax = fmaxf(emax, fabsf(es[k]));
  float lo = 0.f, hi = dmax + 2.f * emax + 1e-6f;
#pragma unroll 1
  for (int iter = 0; iter < 15; ++iter) {
    float mid = 0.5f * (lo + hi);
    float q = dd[0] - mid;
    int cnt = (q < 0.f) ? 1 : 0;
#pragma unroll
    for (int k = 1; k < 16; ++k) {
      q = dd[k] - mid - e2a[k] * __builtin_amdgcn_rcpf(q);
      cnt += (q < 0.f) ? 1 : 0;
    }
    if (cnt > j) hi = mid; else lo = mid;
  }
  float lam = 0.5f * (lo + hi);
  int t = 15 - j;
  fb[(224 + (t >> 3)) * 128 + (t & 7)] = f2bf(sqrtf(fmaxf(lam, 0.f)));
}

// ---------------------------------------------------------------------------
// GEMM1: h1 = relu(feats @ W1 + b1). M=65536, K=1824, N=256.
// M64 x N256 tile, grid 1024 -> 4 blocks/CU (was grid-limited at 2).
// feats still read once; W1t re-reads are L2-resident. 20 KB LDS.
// ---------------------------------------------------------------------------
__global__ __launch_bounds__(256, 4) void gemm1_kernel(const u16* __restrict__ feats,
                                                       const u16* __restrict__ w1t,
                                                       const float* __restrict__ b1,
                                                       u16* __restrict__ h1) {
  __shared__ __align__(16) u16 At[4 * 512];    // 4 KB  [rt_local][g][r][e]
  __shared__ __align__(16) u16 Bt[16 * 512];   // 16 KB [ct_local][g][c][e]
  const int tid = threadIdx.x, lane = tid & 63, wv = tid >> 6;
  const int l15 = lane & 15, q4 = lane >> 4;
  const int m0 = blockIdx.x * 64;
  const int wn = wv * 64;                      // wave's 64-col strip

  // staging: A 1 instr/wave (wave wv stages rt_local=wv), B 4 instr/wave
  const u16* gA = feats + (size_t)((m0 >> 4) + wv) * 29184 + lane * 8;
  u16* lA = At + wv * 512;
  const u16* gB[4]; u16* lB[4];
#pragma unroll
  for (int j = 0; j < 4; ++j) {
    int ct = wv * 4 + j;
    gB[j] = w1t + (size_t)ct * 29184 + lane * 8;
    lB[j] = Bt + ct * 512;
  }

  v4f acc[4][4];
#pragma unroll
  for (int mt = 0; mt < 4; ++mt)
#pragma unroll
    for (int nt = 0; nt < 4; ++nt)
#pragma unroll
      for (int r = 0; r < 4; ++r) acc[mt][nt][r] = 0.f;

  for (int k0 = 0; k0 < FEAT_PAD; k0 += 32) {
    const int go = (k0 >> 3) * 128;
    gl_lds16(gA + go, lA);
#pragma unroll
    for (int j = 0; j < 4; ++j) gl_lds16(gB[j] + go, lB[j]);
    __syncthreads();

    short8 af[4], bfr[4];
#pragma unroll
    for (int mt = 0; mt < 4; ++mt)
      af[mt] = *(const short8*)(At + mt * 512 + q4 * 128 + l15 * 8);
#pragma unroll
    for (int nt = 0; nt < 4; ++nt)
      bfr[nt] = *(const short8*)(Bt + ((wn >> 4) + nt) * 512 + q4 * 128 + l15 * 8);
#pragma unroll
    for (int mt = 0; mt < 4; ++mt)
#pragma unroll
      for (int nt = 0; nt < 4; ++nt)
        acc[mt][nt] = mfma16(af[mt], bfr[nt], acc[mt][nt]);
    __syncthreads();
  }

  // epilogue: bias+relu, row-major h1 (proven full-sector pattern)
#pragma unroll
  for (int mt = 0; mt < 4; ++mt)
#pragma unroll
    for (int nt = 0; nt < 4; ++nt) {
      int col = wn + nt * 16 + l15;
      float bias = b1[col];
#pragma unroll
      for (int r = 0; r < 4; ++r) {
        int row = m0 + mt * 16 + q4 * 4 + r;
        h1[(size_t)row * 256 + col] = f2bf(fmaxf(acc[mt][nt][r] + bias, 0.f));
      }
    }
}

// ---------------------------------------------------------------------------
// GEMM23: fused layers 2-4, barrier-free; A-frags from ROW-MAJOR h1. (unchanged)
// ---------------------------------------------------------------------------
__global__ __launch_bounds__(256, 2) void gemm23_kernel(
    const u16* __restrict__ h1, const u16* __restrict__ w2t, const float* __restrict__ b2,
    const u16* __restrict__ w3t, const float* __restrict__ b3,
    const float* __restrict__ w4, const float* __restrict__ b4, float* __restrict__ out) {
  __shared__ __align__(16) u16 H2[128 * 136];
  const int tid = threadIdx.x, lane = tid & 63, wv = tid >> 6;
  const int l15 = lane & 15, q4 = lane >> 4;
  const int m0 = blockIdx.x * 128;

  const u16* pA[2];
#pragma unroll
  for (int mt = 0; mt < 2; ++mt)
    pA[mt] = h1 + (size_t)(m0 + wv * 32 + mt * 16 + l15) * 256 + q4 * 8;
  const u16* pB[8];
#pragma unroll
  for (int nt = 0; nt < 8; ++nt)
    pB[nt] = w2t + (size_t)nt * 4096 + q4 * 128 + l15 * 8;

  v4f acc[2][8];
#pragma unroll
  for (int mt = 0; mt < 2; ++mt)
#pragma unroll
    for (int nt = 0; nt < 8; ++nt)
#pragma unroll
      for (int r = 0; r < 4; ++r) acc[mt][nt][r] = 0.f;

#pragma unroll
  for (int kk = 0; kk < 8; ++kk) {
    short8 af[2], bfr[8];
#pragma unroll
    for (int mt = 0; mt < 2; ++mt) af[mt] = *(const short8*)(pA[mt] + kk * 32);
#pragma unroll
    for (int nt = 0; nt < 8; ++nt) bfr[nt] = *(const short8*)(pB[nt] + kk * 512);
#pragma unroll
    for (int mt = 0; mt < 2; ++mt)
#pragma unroll
      for (int nt = 0; nt < 8; ++nt)
        acc[mt][nt] = mfma16(af[mt], bfr[nt], acc[mt][nt]);
  }

#pragma unroll
  for (int mt = 0; mt < 2; ++mt)
#pragma unroll
    for (int nt = 0; nt < 8; ++nt) {
      int c = nt * 16 + l15;
      float bias = b2[c];
#pragma unroll
      for (int r = 0; r < 4; ++r) {
        int rl = wv * 32 + mt * 16 + q4 * 4 + r;
        H2[rl * 136 + c] = f2bf(fmaxf(acc[mt][nt][r] + bias, 0.f));
      }
    }

  v4f acc2[2][4];
#pragma unroll
  for (int mt = 0; mt < 2; ++mt)
#pragma unroll
    for (int nt = 0; nt < 4; ++nt)
#pragma unroll
      for (int r = 0; r < 4; ++r) acc2[mt][nt][r] = 0.f;
#pragma unroll
  for (int kk = 0; kk < 4; ++kk) {
    short8 af2[2], bf2v[4];
#pragma unroll
    for (int mt = 0; mt < 2; ++mt)
      af2[mt] = *(const short8*)(H2 + (wv * 32 + mt * 16 + l15) * 136 + kk * 32 + q4 * 8);
#pragma unroll
    for (int nt = 0; nt < 4; ++nt)
      bf2v[nt] = *(const short8*)(w3t + (size_t)nt * 2048 + (kk * 4 + q4) * 128 + l15 * 8);
#pragma unroll
    for (int mt = 0; mt < 2; ++mt)
#pragma unroll
      for (int nt = 0; nt < 4; ++nt)
        acc2[mt][nt] = mfma16(af2[mt], bf2v[nt], acc2[mt][nt]);
  }

  float b4v = b4[0];
#pragma unroll
  for (int mt = 0; mt < 2; ++mt)
#pragma unroll
    for (int r = 0; r < 4; ++r) {
      float p = 0.f;
#pragma unroll
      for (int nt = 0; nt < 4; ++nt) {
        int c = nt * 16 + l15;
        float h3 = fmaxf(acc2[mt][nt][r] + b3[c], 0.f);
        p += h3 * w4[c];
      }
      p += __shfl_xor(p, 1);
      p += __shfl_xor(p, 2);
      p += __shfl_xor(p, 4);
      p += __shfl_xor(p, 8);
      if (l15 == 0) {
        int row = m0 + wv * 32 + mt * 16 + q4 * 4 + r;
        out[row] = p + b4v;
      }
    }
}

// ---------------------------------------------------------------------------
extern "C" void kernel_launch(void* const* d_in, const int* in_sizes, int n_in,
                              void* d_out, int out_size, void* d_ws, size_t ws_size,
                              hipStream_t stream) {
  const float* x  = (const float*)d_in[0];
  const float* W1 = (const float*)d_in[1];
  const float* b1 = (const float*)d_in[2];
  const float* W2 = (const float*)d_in[3];
  const float* b2 = (const float*)d_in[4];
  const float* W3 = (const float*)d_in[5];
  const float* b3 = (const float*)d_in[6];
  const float* W4 = (const float*)d_in[7];
  const float* b4 = (const float*)d_in[8];
  float* out = (float*)d_out;

  char* ws = (char*)d_ws;
  u16* feats = (u16*)ws;                                  // 239,075,328 B
  u16* h1    = (u16*)(ws + 239075328ull);                 //  33,554,432 B (row-major)
  u16* w1t   = (u16*)(ws + 239075328ull + 33554432ull);   //     933,888 B
  u16* w2t   = (u16*)(ws + 239075328ull + 33554432ull + 933888ull);            // 65,536
  u16* w3t   = (u16*)(ws + 239075328ull + 33554432ull + 933888ull + 65536ull); // 16,384

  prep_kernel<<<1824, 256, 0, stream>>>(W1, W2, W3, w1t, w2t, w3t);
  feat_kernel<<<4096, 256, 0, stream>>>(x, feats);
  svd_kernel<<<4096, 256, 0, stream>>>(feats);
  gemm1_kernel<<<1024, 256, 0, stream>>>(feats, w1t, b1, h1);
  gemm23_kernel<<<512, 256, 0, stream>>>(h1, w2t, b2, w3t, b3, W4, b4, out);
}

// Round 10
// 419.182 us; speedup vs baseline: 1.2783x; 1.2783x over previous
//
#include <hip/hip_runtime.h>
#include <hip/hip_bf16.h>
#include <cstdint>
#include <cstddef>

typedef unsigned short u16;
typedef unsigned int u32;
typedef short short8 __attribute__((ext_vector_type(8)));
typedef short short4v __attribute__((ext_vector_type(4)));
typedef __bf16 bf16x8 __attribute__((ext_vector_type(8)));
typedef float v4f __attribute__((ext_vector_type(4)));
typedef float v16f __attribute__((ext_vector_type(16)));

#define NSAMP 65536
#define FEAT_PAD 1824   // 228 groups of 8

// ---- Layouts ----
// feats_t [rt=s>>4][g=kp>>3][r=s&15][e=kp&7]: elem addr = rt*29184 + g*128 + r*8 + e
// w1t_t   [ct=n>>4][g][c][e]:                 addr = ct*29184 + g*128 + c*8 + e
// h1      ROW-MAJOR [s][n] (65536 x 256)
// w2t_t   [ct][g][c][e] (128 cols, K=256):    addr = ct*4096  + g*128 + c*8 + e
// w3t_t   [ct][g][c][e] (64 cols, K=128):     addr = ct*2048  + g*128 + c*8 + e
// Intra-gram kp permutation (validated R3-R9):
//   kp in [512,1536): kp = 512 + lane*16 + rr  <-> orig 512 + i*32 + j,
//        j=lane&31, i=(rr&3)+8*(rr>>2)+4*(lane>>5)
//   kp in [1536,1792): kp = 1536 + lane*4 + rr <-> orig 1536 + i*16 + j,
//        j=lane&15, i=(lane>>4)*4+rr
//   sv at kp [1792,1808) natural, zeros [1808,1824)

__device__ __forceinline__ u16 f2bf(float f) {
  union { float f; u32 u; } v; v.f = f;
  u32 r = (v.u + 0x7FFFu + ((v.u >> 16) & 1u)) >> 16;  // RTNE
  return (u16)r;
}
__device__ __forceinline__ float bf2f(u16 h) {
  union { u32 u; float f; } v; v.u = ((u32)h) << 16;
  return v.f;
}

__device__ __forceinline__ v4f mfma16(short8 a, short8 b, v4f c) {
  return __builtin_amdgcn_mfma_f32_16x16x32_bf16(
      __builtin_bit_cast(bf16x8, a), __builtin_bit_cast(bf16x8, b), c, 0, 0, 0);
}
__device__ __forceinline__ v16f mfma32(short8 a, short8 b, v16f c) {
  return __builtin_amdgcn_mfma_f32_32x32x16_bf16(
      __builtin_bit_cast(bf16x8, a), __builtin_bit_cast(bf16x8, b), c, 0, 0, 0);
}

// async global->LDS, 16 B/lane; per-lane global addr, wave-uniform LDS base
typedef __attribute__((address_space(1))) const void* gas_ptr;
typedef __attribute__((address_space(3))) void* las_ptr;
__device__ __forceinline__ void gl_lds16(const void* g, void* l) {
  __builtin_amdgcn_global_load_lds((gas_ptr)g, (las_ptr)l, 16, 0, 0);
}

// ---------------------------------------------------------------------------
// Weight prep -> fragment-tiled W1t/W2t/W3t. (unchanged)
// ---------------------------------------------------------------------------
__global__ void prep_kernel(const float* __restrict__ W1, const float* __restrict__ W2,
                            const float* __restrict__ W3,
                            u16* __restrict__ w1t, u16* __restrict__ w2t, u16* __restrict__ w3t) {
  int idx = blockIdx.x * 256 + threadIdx.x;
  if (idx < 256 * FEAT_PAD) {
    int n = idx / FEAT_PAD, kp = idx % FEAT_PAD;
    int k;
    if (kp < 512) {
      k = kp;
    } else if (kp < 1536) {
      int t = kp - 512, ln = t >> 4, rr = t & 15;
      int jj = ln & 31, q2 = ln >> 5;
      int i = (rr & 3) + 8 * (rr >> 2) + 4 * q2;
      k = 512 + i * 32 + jj;
    } else if (kp < 1792) {
      int t = kp - 1536, ln = t >> 2, rr = t & 3;
      int jj = ln & 15;
      int i = (ln >> 4) * 4 + rr;
      k = 1536 + i * 16 + jj;
    } else {
      k = kp;
    }
    size_t addr = (size_t)(n >> 4) * 29184 + (kp >> 3) * 128 + (n & 15) * 8 + (kp & 7);
    w1t[addr] = (kp < 1808) ? f2bf(W1[(size_t)k * 256 + n]) : (u16)0;
  }
  if (idx < 128 * 256) {
    int n = idx / 256, k = idx % 256;
    size_t addr = (size_t)(n >> 4) * 4096 + (k >> 3) * 128 + (n & 15) * 8 + (k & 7);
    w2t[addr] = f2bf(W2[k * 128 + n]);
  }
  if (idx < 64 * 128) {
    int n = idx / 128, k = idx % 128;
    size_t addr = (size_t)(n >> 4) * 2048 + (k >> 3) * 128 + (n & 15) * 8 + (k & 7);
    w3t[addr] = f2bf(W3[k * 64 + n]);
  }
}

// ---------------------------------------------------------------------------
// Fused SVD for 4 samples (quad t <-> sample s0+t). aR[t] = sample t's 16x16
// gram MFMA C-frag (fp32, pre-rounding). Lane j of each 16-lane group runs
// column j of Householder tridiagonalization + parallel Sturm bisection.
// (R5-verified; pure DS+VALU, no memory except the final 2 B sv store.)
// ---------------------------------------------------------------------------
__device__ __forceinline__ void svd4(const v4f* aR, u16* tb, int s0, int lane) {
  const int j = lane & 15, bse = lane & 48, q = lane >> 4;
  float a[16];
#pragma unroll
  for (int gi = 0; gi < 4; ++gi)
#pragma unroll
    for (int r = 0; r < 4; ++r) {
      float t0 = __shfl(aR[0][r], gi * 16 + j);
      float t1 = __shfl(aR[1][r], gi * 16 + j);
      float t2 = __shfl(aR[2][r], gi * 16 + j);
      float t3 = __shfl(aR[3][r], gi * 16 + j);
      a[gi * 4 + r] = (q == 0) ? t0 : (q == 1) ? t1 : (q == 2) ? t2 : t3;
    }

  float es[16];
#pragma unroll
  for (int i = 0; i < 16; ++i) es[i] = 0.f;

#pragma unroll
  for (int step = 0; step < 14; ++step) {
    const int i = 15 - step, l = i - 1;
    float xv = a[i];
    float xm = (j <= l) ? xv : 0.f;
    float h = xm * xm;
    h += __shfl_xor(h, 1); h += __shfl_xor(h, 2);
    h += __shfl_xor(h, 4); h += __shfl_xor(h, 8);
    float ul = __shfl(xm, bse + l);
    float sq = sqrtf(h);
    float alpha = (ul >= 0.f) ? -sq : sq;
    float denom = h - ul * alpha;
    float beta = (h > 1e-30f) ? (1.0f / denom) : 0.f;
    float v = (j < l) ? xm : ((j == l) ? (xm - alpha) : 0.f);
    float vv[16], pp[16];
#pragma unroll
    for (int m = 0; m < 16; ++m) vv[m] = (m < i) ? __shfl(v, bse + m) : 0.f;
    float p = 0.f;
#pragma unroll
    for (int m = 0; m < 16; ++m) if (m < i) p = fmaf(a[m], vv[m], p);
    p *= beta;
#pragma unroll
    for (int m = 0; m < 16; ++m) pp[m] = (m <= i) ? __shfl(p, bse + m) : 0.f;
    float Ks = 0.f;
#pragma unroll
    for (int m = 0; m < 16; ++m) if (m < i) Ks = fmaf(pp[m], vv[m], Ks);
    Ks *= 0.5f * beta;
    float wsc = p - Ks * v;
#pragma unroll
    for (int m = 0; m <= 15; ++m) {
      if (m <= i) {
        float wm = pp[m] - Ks * vv[m];
        a[m] -= vv[m] * wsc + wm * v;
      }
    }
    es[i] = alpha;
  }
  es[1] = __shfl(a[1], bse + 0);

  float dsel = a[0];
#pragma unroll
  for (int m = 1; m < 16; ++m) dsel = (j == m) ? a[m] : dsel;
  float dd[16];
#pragma unroll
  for (int m = 0; m < 16; ++m) dd[m] = __shfl(dsel, bse + m);
  float e2a[16];
  e2a[0] = 0.f;
#pragma unroll
  for (int k = 1; k < 16; ++k) e2a[k] = es[k] * es[k] + 1e-30f;
  float dmax = dd[0], emax = 0.f;
#pragma unroll
  for (int m = 1; m < 16; ++m) dmax = fmaxf(dmax, dd[m]);
#pragma unroll
  for (int k = 1; k < 16; ++k) emax = fmaxf(emax, fabsf(es[k]));
  float lo = 0.f, hi = dmax + 2.f * emax + 1e-6f;
#pragma unroll 1
  for (int iter = 0; iter < 15; ++iter) {
    float mid = 0.5f * (lo + hi);
    float qq = dd[0] - mid;
    int cnt = (qq < 0.f) ? 1 : 0;
#pragma unroll
    for (int k = 1; k < 16; ++k) {
      qq = dd[k] - mid - e2a[k] * __builtin_amdgcn_rcpf(qq);
      cnt += (qq < 0.f) ? 1 : 0;
    }
    if (cnt > j) hi = mid; else lo = mid;
  }
  float lam = 0.5f * (lo + hi);
  int t = 15 - j;                       // descending order
  int s = s0 + q;                       // this quad's sample
  tb[(size_t)(224 + (t >> 3)) * 128 + (s & 15) * 8 + (t & 7)] = f2bf(sqrtf(fmaxf(lam, 0.f)));
}

// ---------------------------------------------------------------------------
// Feature kernel: ONE 4-sample qtr per wave (16384 independent waves) WITH
// fused svd4 tail. Memory phase (loads/stores) of co-resident waves hides
// the svd's DS+VALU compute; svd gram comes from pre-rounded fp32 MFMA accs.
// ---------------------------------------------------------------------------
__global__ __launch_bounds__(256) void feat_kernel(const float* __restrict__ x,
                                                   u16* __restrict__ feats) {
  const int lane = threadIdx.x & 63;
  const int wv = threadIdx.x >> 6;      // qtr index 0..3
  const int wid = blockIdx.x;           // tile 0..4095
  const int l15 = lane & 15, l31 = lane & 31, q4 = lane >> 4, q2 = lane >> 5;
  const int pbase = l15 * 32 + q4 * 8;
  u16* tb = feats + (size_t)wid * 29184;

  short8 sx[4], sc0[4], sc1[4];
  short4v sr4[4];
  v4f aR[4];
#pragma unroll
  for (int r8 = 0; r8 < 4; ++r8) {
    const int s = wid * 16 + wv * 4 + r8;
    const float* xs = x + (size_t)s * 512;
    float4 p0 = *(const float4*)(xs + pbase);
    float4 p1 = *(const float4*)(xs + pbase + 4);
    float t[8];
#pragma unroll
    for (int j = 0; j < 8; ++j) t[j] = xs[(q2 * 8 + j) * 32 + l31];

    short8 fp, ft;
    fp[0] = (short)f2bf(p0.x); fp[1] = (short)f2bf(p0.y);
    fp[2] = (short)f2bf(p0.z); fp[3] = (short)f2bf(p0.w);
    fp[4] = (short)f2bf(p1.x); fp[5] = (short)f2bf(p1.y);
    fp[6] = (short)f2bf(p1.z); fp[7] = (short)f2bf(p1.w);
#pragma unroll
    for (int j = 0; j < 8; ++j) ft[j] = (short)f2bf(t[j]);

    v4f accR; v16f accC;
#pragma unroll
    for (int r = 0; r < 4; ++r) accR[r] = 0.f;
#pragma unroll
    for (int r = 0; r < 16; ++r) accC[r] = 0.f;
    accR = mfma16(fp, fp, accR);   // Gr = P P^T (fp32)
    accC = mfma32(ft, ft, accC);   // Gc = P^T P

    sx[r8] = fp;
#pragma unroll
    for (int r = 0; r < 8; ++r) { sc0[r8][r] = (short)f2bf(accC[r]); sc1[r8][r] = (short)f2bf(accC[r + 8]); }
#pragma unroll
    for (int r = 0; r < 4; ++r) sr4[r8][r] = (short)f2bf(accR[r]);
    aR[r8] = accR;
  }

  // stores first (fire-and-forget; drain overlaps the svd tail below)
  const int ho = wv * 4;
#pragma unroll
  for (int r8 = 0; r8 < 4; ++r8)
    *(short8*)(tb + (l15 * 4 + q4) * 128 + (ho + r8) * 8) = sx[r8];
#pragma unroll
  for (int r8 = 0; r8 < 4; ++r8)
    *(short8*)(tb + (64 + lane * 2) * 128 + (ho + r8) * 8) = sc0[r8];
#pragma unroll
  for (int r8 = 0; r8 < 4; ++r8)
    *(short8*)(tb + (65 + lane * 2) * 128 + (ho + r8) * 8) = sc1[r8];
#pragma unroll
  for (int r8 = 0; r8 < 4; ++r8)
    *(short4v*)(tb + (192 + (lane >> 1)) * 128 + (lane & 1) * 4 + (ho + r8) * 8) = sr4[r8];

  if (wv == 3 && lane < 32) {  // zero pad groups 226,227
    short8 z;
#pragma unroll
    for (int j = 0; j < 8; ++j) z[j] = 0;
    *(short8*)(tb + 226 * 128 + lane * 8) = z;
  }

  svd4(aR, tb, wid * 16 + ho, lane);  // sv for this wave's 4 samples
}

// ---------------------------------------------------------------------------
// GEMM1: h1 = relu(feats @ W1 + b1). M=65536, K=1824, N=256.
// R8-exact config (measured ~95 us): M128 tile, (256,2), 24 KB LDS,
// global_load_lds staging, row-major h1 epilogue (WRITE 33 MB).
// ---------------------------------------------------------------------------
__global__ __launch_bounds__(256, 2) void gemm1_kernel(const u16* __restrict__ feats,
                                                       const u16* __restrict__ w1t,
                                                       const float* __restrict__ b1,
                                                       u16* __restrict__ h1) {
  __shared__ __align__(16) u16 At[8 * 512];    // 8 KB  [rt_local][g][r][e]
  __shared__ __align__(16) u16 Bt[16 * 512];   // 16 KB [ct_local][g][c][e]
  const int tid = threadIdx.x, lane = tid & 63, wv = tid >> 6;
  const int l15 = lane & 15, q4 = lane >> 4;
  const int m0 = blockIdx.x * 128;
  const int wm = (wv & 1) * 64, wn = (wv >> 1) * 128;

  const u16* gA[2]; u16* lA[2];
#pragma unroll
  for (int j = 0; j < 2; ++j) {
    int i = wv * 2 + j;
    gA[j] = feats + (size_t)((m0 >> 4) + i) * 29184 + lane * 8;
    lA[j] = At + i * 512;
  }
  const u16* gB[4]; u16* lB[4];
#pragma unroll
  for (int j = 0; j < 4; ++j) {
    int i = wv * 4 + j;
    gB[j] = w1t + (size_t)i * 29184 + lane * 8;
    lB[j] = Bt + i * 512;
  }

  v4f acc[4][8];
#pragma unroll
  for (int mt = 0; mt < 4; ++mt)
#pragma unroll
    for (int nt = 0; nt < 8; ++nt)
#pragma unroll
      for (int r = 0; r < 4; ++r) acc[mt][nt][r] = 0.f;

  for (int k0 = 0; k0 < FEAT_PAD; k0 += 32) {
    const int go = (k0 >> 3) * 128;
#pragma unroll
    for (int j = 0; j < 2; ++j) gl_lds16(gA[j] + go, lA[j]);
#pragma unroll
    for (int j = 0; j < 4; ++j) gl_lds16(gB[j] + go, lB[j]);
    __syncthreads();

    short8 af[4], bfr[8];
#pragma unroll
    for (int mt = 0; mt < 4; ++mt)
      af[mt] = *(const short8*)(At + ((wv & 1) * 4 + mt) * 512 + q4 * 128 + l15 * 8);
#pragma unroll
    for (int nt = 0; nt < 8; ++nt)
      bfr[nt] = *(const short8*)(Bt + ((wv >> 1) * 8 + nt) * 512 + q4 * 128 + l15 * 8);
#pragma unroll
    for (int mt = 0; mt < 4; ++mt)
#pragma unroll
      for (int nt = 0; nt < 8; ++nt)
        acc[mt][nt] = mfma16(af[mt], bfr[nt], acc[mt][nt]);
    __syncthreads();
  }

  // epilogue: bias+relu, row-major h1 (proven full-sector pattern)
#pragma unroll
  for (int mt = 0; mt < 4; ++mt)
#pragma unroll
    for (int nt = 0; nt < 8; ++nt) {
      int col = wn + nt * 16 + l15;
      float bias = b1[col];
#pragma unroll
      for (int r = 0; r < 4; ++r) {
        int row = m0 + wm + mt * 16 + q4 * 4 + r;
        h1[(size_t)row * 256 + col] = f2bf(fmaxf(acc[mt][nt][r] + bias, 0.f));
      }
    }
}

// ---------------------------------------------------------------------------
// GEMM23: fused layers 2-4, barrier-free; A-frags from ROW-MAJOR h1. (unchanged)
// ---------------------------------------------------------------------------
__global__ __launch_bounds__(256, 2) void gemm23_kernel(
    const u16* __restrict__ h1, const u16* __restrict__ w2t, const float* __restrict__ b2,
    const u16* __restrict__ w3t, const float* __restrict__ b3,
    const float* __restrict__ w4, const float* __restrict__ b4, float* __restrict__ out) {
  __shared__ __align__(16) u16 H2[128 * 136];
  const int tid = threadIdx.x, lane = tid & 63, wv = tid >> 6;
  const int l15 = lane & 15, q4 = lane >> 4;
  const int m0 = blockIdx.x * 128;

  const u16* pA[2];
#pragma unroll
  for (int mt = 0; mt < 2; ++mt)
    pA[mt] = h1 + (size_t)(m0 + wv * 32 + mt * 16 + l15) * 256 + q4 * 8;
  const u16* pB[8];
#pragma unroll
  for (int nt = 0; nt < 8; ++nt)
    pB[nt] = w2t + (size_t)nt * 4096 + q4 * 128 + l15 * 8;

  v4f acc[2][8];
#pragma unroll
  for (int mt = 0; mt < 2; ++mt)
#pragma unroll
    for (int nt = 0; nt < 8; ++nt)
#pragma unroll
      for (int r = 0; r < 4; ++r) acc[mt][nt][r] = 0.f;

#pragma unroll
  for (int kk = 0; kk < 8; ++kk) {
    short8 af[2], bfr[8];
#pragma unroll
    for (int mt = 0; mt < 2; ++mt) af[mt] = *(const short8*)(pA[mt] + kk * 32);
#pragma unroll
    for (int nt = 0; nt < 8; ++nt) bfr[nt] = *(const short8*)(pB[nt] + kk * 512);
#pragma unroll
    for (int mt = 0; mt < 2; ++mt)
#pragma unroll
      for (int nt = 0; nt < 8; ++nt)
        acc[mt][nt] = mfma16(af[mt], bfr[nt], acc[mt][nt]);
  }

#pragma unroll
  for (int mt = 0; mt < 2; ++mt)
#pragma unroll
    for (int nt = 0; nt < 8; ++nt) {
      int c = nt * 16 + l15;
      float bias = b2[c];
#pragma unroll
      for (int r = 0; r < 4; ++r) {
        int rl = wv * 32 + mt * 16 + q4 * 4 + r;
        H2[rl * 136 + c] = f2bf(fmaxf(acc[mt][nt][r] + bias, 0.f));
      }
    }

  v4f acc2[2][4];
#pragma unroll
  for (int mt = 0; mt < 2; ++mt)
#pragma unroll
    for (int nt = 0; nt < 4; ++nt)
#pragma unroll
      for (int r = 0; r < 4; ++r) acc2[mt][nt][r] = 0.f;
#pragma unroll
  for (int kk = 0; kk < 4; ++kk) {
    short8 af2[2], bf2v[4];
#pragma unroll
    for (int mt = 0; mt < 2; ++mt)
      af2[mt] = *(const short8*)(H2 + (wv * 32 + mt * 16 + l15) * 136 + kk * 32 + q4 * 8);
#pragma unroll
    for (int nt = 0; nt < 4; ++nt)
      bf2v[nt] = *(const short8*)(w3t + (size_t)nt * 2048 + (kk * 4 + q4) * 128 + l15 * 8);
#pragma unroll
    for (int mt = 0; mt < 2; ++mt)
#pragma unroll
      for (int nt = 0; nt < 4; ++nt)
        acc2[mt][nt] = mfma16(af2[mt], bf2v[nt], acc2[mt][nt]);
  }

  float b4v = b4[0];
#pragma unroll
  for (int mt = 0; mt < 2; ++mt)
#pragma unroll
    for (int r = 0; r < 4; ++r) {
      float p = 0.f;
#pragma unroll
      for (int nt = 0; nt < 4; ++nt) {
        int c = nt * 16 + l15;
        float h3 = fmaxf(acc2[mt][nt][r] + b3[c], 0.f);
        p += h3 * w4[c];
      }
      p += __shfl_xor(p, 1);
      p += __shfl_xor(p, 2);
      p += __shfl_xor(p, 4);
      p += __shfl_xor(p, 8);
      if (l15 == 0) {
        int row = m0 + wv * 32 + mt * 16 + q4 * 4 + r;
        out[row] = p + b4v;
      }
    }
}

// ---------------------------------------------------------------------------
extern "C" void kernel_launch(void* const* d_in, const int* in_sizes, int n_in,
                              void* d_out, int out_size, void* d_ws, size_t ws_size,
                              hipStream_t stream) {
  const float* x  = (const float*)d_in[0];
  const float* W1 = (const float*)d_in[1];
  const float* b1 = (const float*)d_in[2];
  const float* W2 = (const float*)d_in[3];
  const float* b2 = (const float*)d_in[4];
  const float* W3 = (const float*)d_in[5];
  const float* b3 = (const float*)d_in[6];
  const float* W4 = (const float*)d_in[7];
  const float* b4 = (const float*)d_in[8];
  float* out = (float*)d_out;

  char* ws = (char*)d_ws;
  u16* feats = (u16*)ws;                                  // 239,075,328 B
  u16* h1    = (u16*)(ws + 239075328ull);                 //  33,554,432 B (row-major)
  u16* w1t   = (u16*)(ws + 239075328ull + 33554432ull);   //     933,888 B
  u16* w2t   = (u16*)(ws + 239075328ull + 33554432ull + 933888ull);            // 65,536
  u16* w3t   = (u16*)(ws + 239075328ull + 33554432ull + 933888ull + 65536ull); // 16,384

  prep_kernel<<<1824, 256, 0, stream>>>(W1, W2, W3, w1t, w2t, w3t);
  feat_kernel<<<4096, 256, 0, stream>>>(x, feats);
  gemm1_kernel<<<512, 256, 0, stream>>>(feats, w1t, b1, h1);
  gemm23_kernel<<<512, 256, 0, stream>>>(h1, w2t, b2, w3t, b3, W4, b4, out);
}